// Round 2
// baseline (106.128 us; speedup 1.0000x reference)
//
#include <hip/hip_runtime.h>
#include <stdint.h>

typedef float f32x4 __attribute__((ext_vector_type(4)));
typedef short short8 __attribute__((ext_vector_type(8)));
typedef short short4v __attribute__((ext_vector_type(4)));

#define N_SPATIAL 65536   // 256*256
#define DIM 256
#define GROUPS 32
#define HIDDEN 128

__device__ __forceinline__ float b2f(uint16_t u) {
  union { uint32_t u; float f; } v; v.u = ((uint32_t)u) << 16; return v.f;
}
__device__ __forceinline__ uint16_t f2b(float f) {
  union { float f; uint32_t u; } v; v.f = f;
  uint32_t r = (v.u + 0x7FFFu + ((v.u >> 16) & 1u)) >> 16;
  return (uint16_t)r;
}

// ---------------------------------------------------------------------------
// K1: transpose x (c,n) fp32 -> xT (n,c) bf16, plus GroupNorm partial stats.
// grid 1024 (64-n tiles), block 256.
__global__ __launch_bounds__(256) void k1_transpose_stats(
    const float* __restrict__ x, uint16_t* __restrict__ xT, float* __restrict__ gnp) {
  __shared__ uint16_t xs[64][264];   // [n][c] padded stride 264
  const int t = threadIdx.x;
  const int n0 = blockIdx.x * 64;
  const int c_l = (t >> 2) & 15;
  const int nq  = (t & 3) + 4 * (t >> 6);
  for (int p = 0; p < 16; ++p) {
    int c = 16 * p + c_l;
    float4 v = *(const float4*)(x + (size_t)c * N_SPATIAL + n0 + nq * 4);
    int nn = nq * 4;
    xs[nn + 0][c] = f2b(v.x); xs[nn + 1][c] = f2b(v.y);
    xs[nn + 2][c] = f2b(v.z); xs[nn + 3][c] = f2b(v.w);
  }
  __syncthreads();
  {
    int g = t >> 3; int c = g * 8 + (t & 7);
    float s = 0.f, ss = 0.f;
    for (int n = 0; n < 64; ++n) { float f = b2f(xs[n][c]); s += f; ss += f * f; }
    s  += __shfl_xor(s, 1, 64);  ss += __shfl_xor(ss, 1, 64);
    s  += __shfl_xor(s, 2, 64);  ss += __shfl_xor(ss, 2, 64);
    s  += __shfl_xor(s, 4, 64);  ss += __shfl_xor(ss, 4, 64);
    if ((t & 7) == 0) {
      gnp[((size_t)blockIdx.x * 32 + g) * 2 + 0] = s;
      gnp[((size_t)blockIdx.x * 32 + g) * 2 + 1] = ss;
    }
  }
  for (int p = 0; p < 8; ++p) {
    int j = t + 256 * p; int n = j >> 5; int c16 = j & 31;
    f32x4 val = *(const f32x4*)((const char*)&xs[0][0] + n * 528 + c16 * 16);
    *(f32x4*)((char*)xT + ((size_t)(n0 + n)) * 512 + c16 * 16) = val;
  }
}

// ---------------------------------------------------------------------------
// K2: reduce stats partials -> per-channel a,b.  grid 32, block 256.
__global__ __launch_bounds__(256) void k2_stats_final(
    const float* __restrict__ gnp, const float* __restrict__ gnw,
    const float* __restrict__ gnb, float* __restrict__ ab) {
  __shared__ float red[4][2];
  const int g = blockIdx.x; const int t = threadIdx.x;
  float s = 0.f, ss = 0.f;
  for (int c = t; c < 1024; c += 256) {
    s  += gnp[((size_t)c * 32 + g) * 2 + 0];
    ss += gnp[((size_t)c * 32 + g) * 2 + 1];
  }
  for (int m = 32; m >= 1; m >>= 1) { s += __shfl_xor(s, m, 64); ss += __shfl_xor(ss, m, 64); }
  if ((t & 63) == 0) { red[t >> 6][0] = s; red[t >> 6][1] = ss; }
  __syncthreads();
  if (t == 0) {
    float S  = red[0][0] + red[1][0] + red[2][0] + red[3][0];
    float SS = red[0][1] + red[1][1] + red[2][1] + red[3][1];
    const float invN = 1.0f / 524288.0f;
    float mean = S * invN;
    float var  = SS * invN - mean * mean;
    float rs   = rsqrtf(var + 1e-5f);
    for (int i = 0; i < 8; ++i) {
      int c = g * 8 + i;
      float aa = gnw[c] * rs;
      ab[c] = aa;
      ab[256 + c] = gnb[c] - mean * aa;
    }
  }
}

// ---------------------------------------------------------------------------
// K2b: fold norm into qkv weights: W'[o][c]=W*a (bf16), bias'[o]=qb[o]+sum W*b.
// grid 384, block 64.
__global__ __launch_bounds__(64) void k2b_fold_w(
    const float* __restrict__ qw, const float* __restrict__ qb,
    const float* __restrict__ ab, uint16_t* __restrict__ wp, float* __restrict__ biasp) {
  const int o = blockIdx.x; const int l = threadIdx.x;
  float4 w  = *(const float4*)(qw + (size_t)o * 256 + l * 4);
  float4 av = *(const float4*)(ab + l * 4);
  float4 bv = *(const float4*)(ab + 256 + l * 4);
  short4v pk;
  pk[0] = (short)f2b(w.x * av.x); pk[1] = (short)f2b(w.y * av.y);
  pk[2] = (short)f2b(w.z * av.z); pk[3] = (short)f2b(w.w * av.w);
  *(short4v*)(wp + (size_t)o * 256 + l * 4) = pk;
  float part = w.x * bv.x + w.y * bv.y + w.z * bv.z + w.w * bv.w;
  for (int m = 32; m >= 1; m >>= 1) part += __shfl_xor(part, m, 64);
  if (l == 0) biasp[o] = qb[o] + part;
}

// ---------------------------------------------------------------------------
// K3: qkv = W'(384x256) @ x(256x65536) + bias'.  MFMA bf16, 128x128 tiles.
// m-tile 0 -> q transposed to qT[n][128] bf16 ; m-tiles 1,2 -> kv[o-128][n] bf16.
// grid 1536, block 256.
__global__ __launch_bounds__(256) void k3_qkv(
    const uint16_t* __restrict__ xT, const uint16_t* __restrict__ wp,
    const float* __restrict__ biasp, uint16_t* __restrict__ kv, uint16_t* __restrict__ qT) {
  __shared__ __align__(16) char smem[32768];   // A:[0,16K) B:[16K,32K); reused as tbuf
  const int t = threadIdx.x;
  const int bid = blockIdx.x;
  const int mt = bid % 3;
  const int nt = bid / 3;
  const int o0 = mt * 128, n0 = nt * 128;
  const int l = t & 63, wid = t >> 6, wr = wid >> 1, wc = wid & 1;
  const int lrow = l & 15, lk = l >> 4, lr7 = lrow & 7;
  const int srow = t >> 3, sch = t & 7;
  const int chs = sch ^ (srow & 7);

  f32x4 acc[4][4] = {};

  for (int ks = 0; ks < 4; ++ks) {
    const int k0 = ks * 64;
    __syncthreads();
    #pragma unroll
    for (int p = 0; p < 4; ++p) {
      int row = srow + 32 * p;
      f32x4 va = *(const f32x4*)((const char*)wp + (size_t)(o0 + row) * 512 + k0 * 2 + sch * 16);
      *(f32x4*)(&smem[row * 128 + chs * 16]) = va;
      f32x4 vb = *(const f32x4*)((const char*)xT + (size_t)(n0 + row) * 512 + k0 * 2 + sch * 16);
      *(f32x4*)(&smem[16384 + row * 128 + chs * 16]) = vb;
    }
    __syncthreads();
    #pragma unroll
    for (int kk = 0; kk < 2; ++kk) {
      short8 a[4], b[4];
      #pragma unroll
      for (int m = 0; m < 4; ++m) {
        int row = wr * 64 + m * 16 + lrow;
        a[m] = *(const short8*)(&smem[row * 128 + (((kk * 4 + lk) ^ lr7) << 4)]);
      }
      #pragma unroll
      for (int n = 0; n < 4; ++n) {
        int row = wc * 64 + n * 16 + lrow;
        b[n] = *(const short8*)(&smem[16384 + row * 128 + (((kk * 4 + lk) ^ lr7) << 4)]);
      }
      #pragma unroll
      for (int m = 0; m < 4; ++m)
        #pragma unroll
        for (int n = 0; n < 4; ++n)
          acc[m][n] = __builtin_amdgcn_mfma_f32_16x16x32_bf16(a[m], b[n], acc[m][n], 0, 0, 0);
    }
  }

  if (mt == 0) {
    // q path: add bias, transpose through LDS, emit qT[n][d] bf16 coalesced
    __syncthreads();
    #pragma unroll
    for (int m = 0; m < 4; ++m) {
      int ob = wr * 64 + m * 16 + lk * 4;
      float b0 = biasp[ob + 0], b1 = biasp[ob + 1], b2 = biasp[ob + 2], b3 = biasp[ob + 3];
      #pragma unroll
      for (int n = 0; n < 4; ++n) {
        int nn = wc * 64 + n * 16 + lrow;
        short4v pk;
        pk[0] = (short)f2b(acc[m][n][0] + b0);
        pk[1] = (short)f2b(acc[m][n][1] + b1);
        pk[2] = (short)f2b(acc[m][n][2] + b2);
        pk[3] = (short)f2b(acc[m][n][3] + b3);
        *(short4v*)(&smem[nn * 256 + ((ob * 2) ^ ((nn & 7) << 4))]) = pk;
      }
    }
    __syncthreads();
    #pragma unroll
    for (int p = 0; p < 8; ++p) {
      int j = t + 256 * p; int n = j >> 4; int o8 = j & 15;
      f32x4 v = *(const f32x4*)(&smem[n * 256 + ((o8 * 16) ^ ((n & 7) << 4))]);
      *(f32x4*)((char*)qT + (size_t)(n0 + n) * 256 + o8 * 16) = v;
    }
  } else {
    // k / v path: add bias, store bf16 (o-128, n)
    #pragma unroll
    for (int m = 0; m < 4; ++m) {
      int ob = o0 + wr * 64 + m * 16 + lk * 4;
      float b0 = biasp[ob + 0], b1 = biasp[ob + 1], b2 = biasp[ob + 2], b3 = biasp[ob + 3];
      #pragma unroll
      for (int n = 0; n < 4; ++n) {
        int nn = n0 + wc * 64 + n * 16 + lrow;
        size_t r0 = (size_t)(ob - 128) * N_SPATIAL + nn;
        kv[r0]                    = f2b(acc[m][n][0] + b0);
        kv[r0 + 1ull * N_SPATIAL] = f2b(acc[m][n][1] + b1);
        kv[r0 + 2ull * N_SPATIAL] = f2b(acc[m][n][2] + b2);
        kv[r0 + 3ull * N_SPATIAL] = f2b(acc[m][n][3] + b3);
      }
    }
  }
}

// ---------------------------------------------------------------------------
// K5: per-head context partials: sum_n exp(k[d,n]) * v[e,n]  and  sum_n exp(k[d,n]).
// grid 512 = 4 heads * 128 chunks (512 n each), block 256.
__global__ __launch_bounds__(256) void k5_context(
    const uint16_t* __restrict__ kv, float* __restrict__ part) {
  __shared__ float ek[128][36];
  __shared__ float vf[128][36];
  const int t = threadIdx.x;
  const int h = blockIdx.x & 3, chunk = blockIdx.x >> 2;
  const int nbase = chunk * 512;
  const int srow = t >> 3, sc16b = t & 7;
  const int d = t >> 3;
  const int eg = (t & 7) * 4;
  f32x4 accv = {0.f, 0.f, 0.f, 0.f};
  float den = 0.f;
  for (int sub = 0; sub < 4; ++sub) {
    int n0 = nbase + sub * 128;
    __syncthreads();
    #pragma unroll
    for (int p = 0; p < 2; ++p) {
      int c16 = sc16b + 8 * p;
      f32x4 kb = *(const f32x4*)((const char*)kv + (size_t)(h * 32 + srow) * 131072 + (size_t)n0 * 2 + c16 * 16);
      const uint16_t* u = (const uint16_t*)&kb;
      #pragma unroll
      for (int i = 0; i < 8; ++i) ek[c16 * 8 + i][srow] = __expf(b2f(u[i]));
      f32x4 vb = *(const f32x4*)((const char*)kv + (size_t)(128 + h * 32 + srow) * 131072 + (size_t)n0 * 2 + c16 * 16);
      const uint16_t* w = (const uint16_t*)&vb;
      #pragma unroll
      for (int i = 0; i < 8; ++i) vf[c16 * 8 + i][srow] = b2f(w[i]);
    }
    __syncthreads();
    for (int n = 0; n < 128; ++n) {
      float kd = ek[n][d];
      f32x4 vv = *(const f32x4*)(&vf[n][eg]);
      accv += kd * vv;
      den += kd;
    }
  }
  float* pp = part + ((size_t)h * 128 + chunk) * 1056;
  pp[d * 32 + eg + 0] = accv[0];
  pp[d * 32 + eg + 1] = accv[1];
  pp[d * 32 + eg + 2] = accv[2];
  pp[d * 32 + eg + 3] = accv[3];
  if (eg == 0) pp[1024 + d] = den;
}

// ---------------------------------------------------------------------------
// K6: reduce context partials over 128 chunks.  grid 17, block 256.
__global__ __launch_bounds__(256) void k6_reduce(
    const float* __restrict__ part, float* __restrict__ ctxs) {
  int id = blockIdx.x * 256 + threadIdx.x;
  if (id >= 4224) return;
  int h = id / 1056; int r = id - h * 1056;
  const float* p = part + (size_t)h * 128 * 1056 + r;
  float s = 0.f;
  for (int c = 0; c < 128; ++c) s += p[(size_t)c * 1056];
  ctxs[h * 1056 + r] = s;
}

// ---------------------------------------------------------------------------
// K6b: fold out_weight with normalized context -> M[o][h*32+d] bf16.
// grid 256, block 128.
__global__ __launch_bounds__(128) void k6b_fold(
    const float* __restrict__ ow, const float* __restrict__ ctxs, uint16_t* __restrict__ Mw) {
  const int o = blockIdx.x; const int t = threadIdx.x;
  const int h = t >> 5, d = t & 31;
  const float* cs = ctxs + h * 1056;
  float den = cs[1024 + d];
  float s = 0.f;
  for (int e = 0; e < 32; ++e) s += ow[(size_t)o * 128 + h * 32 + e] * cs[d * 32 + e];
  Mw[(size_t)o * 128 + t] = f2b(s / den);
}

// ---------------------------------------------------------------------------
// K7: out = M(256x128) @ q(128x65536) + out_bias.  MFMA bf16, 128x128 tiles.
// grid 1024, block 256.
__global__ __launch_bounds__(256) void k7_out(
    const uint16_t* __restrict__ qT, const uint16_t* __restrict__ Mw,
    const float* __restrict__ obias, float* __restrict__ out) {
  __shared__ __align__(16) char smem[32768];
  const int t = threadIdx.x;
  const int bid = blockIdx.x;
  const int mt = bid & 1;
  const int nt = bid >> 1;
  const int o0 = mt * 128, n0 = nt * 128;
  const int l = t & 63, wid = t >> 6, wr = wid >> 1, wc = wid & 1;
  const int lrow = l & 15, lk = l >> 4, lr7 = lrow & 7;
  const int srow = t >> 3, sch = t & 7;
  const int chs = sch ^ (srow & 7);

  f32x4 acc[4][4] = {};

  for (int ks = 0; ks < 2; ++ks) {
    const int k0 = ks * 64;
    __syncthreads();
    #pragma unroll
    for (int p = 0; p < 4; ++p) {
      int row = srow + 32 * p;
      f32x4 va = *(const f32x4*)((const char*)Mw + (size_t)(o0 + row) * 256 + k0 * 2 + sch * 16);
      *(f32x4*)(&smem[row * 128 + chs * 16]) = va;
      f32x4 vb = *(const f32x4*)((const char*)qT + (size_t)(n0 + row) * 256 + k0 * 2 + sch * 16);
      *(f32x4*)(&smem[16384 + row * 128 + chs * 16]) = vb;
    }
    __syncthreads();
    #pragma unroll
    for (int kk = 0; kk < 2; ++kk) {
      short8 a[4], b[4];
      #pragma unroll
      for (int m = 0; m < 4; ++m) {
        int row = wr * 64 + m * 16 + lrow;
        a[m] = *(const short8*)(&smem[row * 128 + (((kk * 4 + lk) ^ lr7) << 4)]);
      }
      #pragma unroll
      for (int n = 0; n < 4; ++n) {
        int row = wc * 64 + n * 16 + lrow;
        b[n] = *(const short8*)(&smem[16384 + row * 128 + (((kk * 4 + lk) ^ lr7) << 4)]);
      }
      #pragma unroll
      for (int m = 0; m < 4; ++m)
        #pragma unroll
        for (int n = 0; n < 4; ++n)
          acc[m][n] = __builtin_amdgcn_mfma_f32_16x16x32_bf16(a[m], b[n], acc[m][n], 0, 0, 0);
    }
  }

  #pragma unroll
  for (int m = 0; m < 4; ++m) {
    int ob = o0 + wr * 64 + m * 16 + lk * 4;
    float b0 = obias[ob + 0], b1 = obias[ob + 1], b2 = obias[ob + 2], b3 = obias[ob + 3];
    #pragma unroll
    for (int n = 0; n < 4; ++n) {
      int nn = n0 + wc * 64 + n * 16 + lrow;
      size_t r0 = (size_t)ob * N_SPATIAL + nn;
      out[r0]                    = acc[m][n][0] + b0;
      out[r0 + 1ull * N_SPATIAL] = acc[m][n][1] + b1;
      out[r0 + 2ull * N_SPATIAL] = acc[m][n][2] + b2;
      out[r0 + 3ull * N_SPATIAL] = acc[m][n][3] + b3;
    }
  }
}

// ---------------------------------------------------------------------------
extern "C" void kernel_launch(void* const* d_in, const int* in_sizes, int n_in,
                              void* d_out, int out_size, void* d_ws, size_t ws_size,
                              hipStream_t stream) {
  const float* x   = (const float*)d_in[0];
  const float* gnw = (const float*)d_in[1];
  const float* gnb = (const float*)d_in[2];
  const float* qw  = (const float*)d_in[3];
  const float* qb  = (const float*)d_in[4];
  const float* ow  = (const float*)d_in[5];
  const float* ob  = (const float*)d_in[6];
  float* out = (float*)d_out;
  char* ws = (char*)d_ws;

  uint16_t* xT    = (uint16_t*)(ws + 0);          // 32 MB
  uint16_t* kv    = (uint16_t*)(ws + 33554432);   // 32 MB
  uint16_t* qT    = (uint16_t*)(ws + 67108864);   // 16 MB
  uint16_t* wp    = (uint16_t*)(ws + 83886080);   // 192 KB
  float*    biasp = (float*)   (ws + 84082688);   // 1.5 KB
  float*    ab    = (float*)   (ws + 84084224);   // 2 KB
  float*    gnp   = (float*)   (ws + 84086272);   // 256 KB
  float*    part  = (float*)   (ws + 84348416);   // 2.1 MB
  float*    ctxs  = (float*)   (ws + 86511104);   // 16.5 KB
  uint16_t* Mw    = (uint16_t*)(ws + 86528000);   // 64 KB

  k1_transpose_stats<<<dim3(1024), dim3(256), 0, stream>>>(x, xT, gnp);
  k2_stats_final<<<dim3(32), dim3(256), 0, stream>>>(gnp, gnw, gnb, ab);
  k2b_fold_w<<<dim3(384), dim3(64), 0, stream>>>(qw, qb, ab, wp, biasp);
  k3_qkv<<<dim3(1536), dim3(256), 0, stream>>>(xT, wp, biasp, kv, qT);
  k5_context<<<dim3(512), dim3(256), 0, stream>>>(kv, part);
  k6_reduce<<<dim3(17), dim3(256), 0, stream>>>(part, ctxs);
  k6b_fold<<<dim3(256), dim3(128), 0, stream>>>(ow, ctxs, Mw);
  k7_out<<<dim3(1024), dim3(256), 0, stream>>>(qT, Mw, ob, out);
}